// Round 14
// baseline (3195.589 us; speedup 1.0000x reference)
//
#include <hip/hip_runtime.h>

#define N_TOK 32768
#define DIN   1024
#define HID   512
#define H2    1024
#define KCB   4096
#define NCB   3
#define CHUNK_E 4096
#define CHUNK_D 8192
#define MARGIN 0.25f   // pass-1 candidate window; ~140 sigma of hi*hi d error

typedef _Float16 f16x8 __attribute__((ext_vector_type(8)));
typedef float f32x4 __attribute__((ext_vector_type(4)));
typedef unsigned short u16;

__device__ inline u16 f2h_bits(float v) {
  union { _Float16 f; u16 u; } cv;
  cv.f = (_Float16)v;
  return cv.u;
}
__device__ inline float h_bits2f(u16 u) {
  union { _Float16 f; u16 u; } cv;
  cv.u = u;
  return (float)cv.f;
}
// split v = hi + (lo/2048); lo stored pre-scaled by 2048 (avoids f16 subnormals)
__device__ inline void fsplit(float v, u16& hi, u16& lo) {
  _Float16 h = (_Float16)v;
  float hf = (float)h;
  union { _Float16 f; u16 u; } ch; ch.f = h; hi = ch.u;
  lo = f2h_bits((v - hf) * 2048.0f);
}

#define SWZ(r) (((r) >> 1) & 3)

__device__ inline void stage16(const u16* gplane, int growbase, int lrowbase,
                               int k0, u16* ldsbase, int l, int stride) {
  const int rp = l >> 2, s = l & 3;
  const int sp = s ^ SWZ(lrowbase + rp);
  const u16* src = gplane + (size_t)(growbase + rp) * stride + k0 + sp * 8;
  __builtin_amdgcn_global_load_lds(
      (const __attribute__((address_space(1))) void*)src,
      (__attribute__((address_space(3))) void*)ldsbase, 16, 0, 0);
}

// ---------------------------------------------------------------------------
// fp32 GEMM, 64x64 tile, k-major aligned LDS — index-critical (r10-proven).
// BIT-EXACT k-order. DO NOT reorder k.
// ---------------------------------------------------------------------------
template <bool RELU, bool SPLIT>
__global__ __launch_bounds__(256) void gemm_f32ek(
    const float* __restrict__ A, const float* __restrict__ B,
    const float* __restrict__ bias, float* __restrict__ C,
    u16* __restrict__ Chi, u16* __restrict__ Clo,
    int M, int K, int Nn) {
  __shared__ float As[16][68];
  __shared__ float Bs[16][68];
  const int tid = threadIdx.x;
  const int tx = tid & 15, ty = tid >> 4;
  const int tx4 = tx * 4, ty4 = ty * 4;
  const int m0 = blockIdx.y * 64, n0 = blockIdx.x * 64;

  const int ar = tid >> 2;
  const int aq = (tid & 3) * 4;
  const int bk = tid >> 4;
  const int bn = (tid & 15) * 4;

  float acc[4][4] = {};

  for (int k0 = 0; k0 < K; k0 += 16) {
    float4 av = *(const float4*)(A + (size_t)(m0 + ar) * K + k0 + aq);
    As[aq + 0][ar] = av.x; As[aq + 1][ar] = av.y;
    As[aq + 2][ar] = av.z; As[aq + 3][ar] = av.w;
    *(float4*)(&Bs[bk][bn]) = *(const float4*)(B + (size_t)(k0 + bk) * Nn + n0 + bn);
    __syncthreads();
#pragma unroll
    for (int kk = 0; kk < 16; ++kk) {
      float4 a4 = *(float4*)(&As[kk][ty4]);
      float4 b4 = *(float4*)(&Bs[kk][tx4]);
      float a[4] = {a4.x, a4.y, a4.z, a4.w};
      float bv[4] = {b4.x, b4.y, b4.z, b4.w};
#pragma unroll
      for (int i = 0; i < 4; ++i)
#pragma unroll
        for (int j = 0; j < 4; ++j) acc[i][j] = fmaf(a[i], bv[j], acc[i][j]);
    }
    __syncthreads();
  }

  float bb[4];
#pragma unroll
  for (int j = 0; j < 4; ++j) bb[j] = bias[n0 + tx4 + j];
#pragma unroll
  for (int i = 0; i < 4; ++i) {
    const size_t row = (size_t)(m0 + ty4 + i);
    if (SPLIT) {
      ushort4 h4, l4;
      u16 hs[4], ls[4];
#pragma unroll
      for (int j = 0; j < 4; ++j) {
        float v = acc[i][j] + bb[j];
        if (RELU) v = v > 0.0f ? v : 0.0f;
        fsplit(v, hs[j], ls[j]);
      }
      h4.x = hs[0]; h4.y = hs[1]; h4.z = hs[2]; h4.w = hs[3];
      l4.x = ls[0]; l4.y = ls[1]; l4.z = ls[2]; l4.w = ls[3];
      *(ushort4*)(&Chi[row * Nn + n0 + tx4]) = h4;
      *(ushort4*)(&Clo[row * Nn + n0 + tx4]) = l4;
    } else {
      float4 o;
      float vv[4];
#pragma unroll
      for (int j = 0; j < 4; ++j) {
        float v = acc[i][j] + bb[j];
        if (RELU) v = v > 0.0f ? v : 0.0f;
        vv[j] = v;
      }
      o.x = vv[0]; o.y = vv[1]; o.z = vv[2]; o.w = vv[3];
      *(float4*)(&C[row * Nn + n0 + tx4]) = o;
    }
  }
}

// ---------------------------------------------------------------------------
// Single-product f16 MFMA GEMM (decoder only).
// ---------------------------------------------------------------------------
template <bool RELU, bool F16OUT>
__global__ __launch_bounds__(256) void gemm_mfma_f16(
    const u16* __restrict__ Ahi, const u16* __restrict__ BThi,
    const float* __restrict__ bias,
    float* __restrict__ C, u16* __restrict__ Chi,
    int M, int K, int Nn) {
  __shared__ __attribute__((aligned(16))) u16 As[64 * 32];
  __shared__ __attribute__((aligned(16))) u16 Bs[128 * 32];
  const int tid = threadIdx.x;
  const int w = tid >> 6, l = tid & 63;
  const int wr = w >> 1, wc = w & 1;
  const int lr = l & 15, g = l >> 4;
  const int m0 = blockIdx.y * 64, n0 = blockIdx.x * 128;

  f32x4 acc[2][4];
#pragma unroll
  for (int mr = 0; mr < 2; ++mr)
#pragma unroll
    for (int nr = 0; nr < 4; ++nr) acc[mr][nr] = (f32x4)0.0f;

  for (int ks = 0; ks < K / 32; ++ks) {
    const int k0 = ks * 32;
    __syncthreads();
    stage16(Ahi, m0 + w * 16, w * 16, k0, As + w * 16 * 32, l, K);
    stage16(BThi, n0 + w * 16, w * 16, k0, Bs + w * 16 * 32, l, K);
    stage16(BThi, n0 + (w + 4) * 16, (w + 4) * 16, k0, Bs + (w + 4) * 16 * 32, l, K);
    __syncthreads();

    f16x8 ah[2], bh[4];
#pragma unroll
    for (int mr = 0; mr < 2; ++mr) {
      const int ra = wr * 32 + mr * 16 + lr;
      ah[mr] = *(const f16x8*)(As + ra * 32 + (g ^ SWZ(ra)) * 8);
    }
#pragma unroll
    for (int nr = 0; nr < 4; ++nr) {
      const int rb = wc * 64 + nr * 16 + lr;
      bh[nr] = *(const f16x8*)(Bs + rb * 32 + (g ^ SWZ(rb)) * 8);
    }
#pragma unroll
    for (int mr = 0; mr < 2; ++mr)
#pragma unroll
      for (int nr = 0; nr < 4; ++nr)
        acc[mr][nr] = __builtin_amdgcn_mfma_f32_16x16x32_f16(
            ah[mr], bh[nr], acc[mr][nr], 0, 0, 0);
  }

#pragma unroll
  for (int nr = 0; nr < 4; ++nr) {
    const int col = n0 + wc * 64 + nr * 16 + lr;
    const float bb = bias[col];
#pragma unroll
    for (int mr = 0; mr < 2; ++mr) {
#pragma unroll
      for (int q = 0; q < 4; ++q) {
        const int row = m0 + wr * 32 + mr * 16 + g * 4 + q;
        float v = acc[mr][nr][q] + bb;
        if (RELU) v = v > 0.0f ? v : 0.0f;
        if (F16OUT) Chi[(size_t)row * Nn + col] = f2h_bits(v);
        else C[(size_t)row * Nn + col] = v;
      }
    }
  }
}

// ---------------------------------------------------------------------------
__global__ __launch_bounds__(256) void wtsplit(
    const float* __restrict__ W, u16* __restrict__ Thi, u16* __restrict__ Tlo,
    int K, int N) {
  __shared__ float tile[32][33];
  const int k0 = blockIdx.y * 32, n0 = blockIdx.x * 32;
  const int c = threadIdx.x & 31, r8 = threadIdx.x >> 5;
#pragma unroll
  for (int p = 0; p < 4; ++p) {
    const int r = r8 + p * 8;
    tile[r][c] = W[(size_t)(k0 + r) * N + n0 + c];
  }
  __syncthreads();
#pragma unroll
  for (int p = 0; p < 4; ++p) {
    const int r = r8 + p * 8;
    float v = tile[c][r];
    u16 hh, ll;
    fsplit(v, hh, ll);
    Thi[(size_t)(n0 + r) * K + k0 + c] = hh;
    Tlo[(size_t)(n0 + r) * K + k0 + c] = ll;
  }
}

// ---------------------------------------------------------------------------
// Codebook split: only HI plane needed (pass-1 hi*hi; pass-2 uses f32 cb).
// ---------------------------------------------------------------------------
__global__ __launch_bounds__(256) void cbsplit_kernel(
    const float* __restrict__ cb, u16* __restrict__ hi) {
  const size_t i4 = (size_t)blockIdx.x * 256 + threadIdx.x;
  float4 v = *(const float4*)(cb + i4 * 4);
  ushort4 h4;
  u16 dummy;
  fsplit(v.x, h4.x, dummy);
  fsplit(v.y, h4.y, dummy);
  fsplit(v.z, h4.z, dummy);
  fsplit(v.w, h4.w, dummy);
  *(ushort4*)(hi + i4 * 4) = h4;
}

// ---------------------------------------------------------------------------
// Codebook squared norms: f64 (exact, for pass-2) + f32 (for pass-1).
// ---------------------------------------------------------------------------
__global__ __launch_bounds__(256) void cnorm_kernel(
    const float* __restrict__ cb, double* __restrict__ cn,
    float* __restrict__ cnf) {
  const int w = blockIdx.x * 4 + (threadIdx.x >> 6);
  const int lane = threadIdx.x & 63;
  const float* row = cb + (size_t)w * HID;
  double s = 0.0;
  for (int h = lane; h < HID; h += 64) {
    double v = (double)row[h];
    s += v * v;
  }
#pragma unroll
  for (int off = 32; off > 0; off >>= 1) s += __shfl_down(s, off, 64);
  if (lane == 0) { cn[w] = s; cnf[w] = (float)s; }
}

// ---------------------------------------------------------------------------
// PASS 1 (screen only — numerics free; exactness lives in pass 2).
// 32-token blocks, 1024 blocks = 4 blocks/CU (r13's 512-block version was
// grid-limited at 2/CU: MfmaUtil 20/VALU 28/HBM 13 = latency-bound).
// Wave w covers code-columns [w*32, w*32+32) of each 128-code chunk.
// Per-thread top-2 per (mr,q) token-slot over its 64-code subset; cross-wave
// LDS merge -> cand[t][32] = top-2 per 256-code subset per lr (IDENTICAL
// layout/guarantee to the r13-proven version; p2 unchanged).
// ---------------------------------------------------------------------------
__global__ __launch_bounds__(256) void rvq_argmin_p1(
    const u16* __restrict__ Ahi, const u16* __restrict__ Bhi,
    const float* __restrict__ cnf, float* __restrict__ cand) {
  __shared__ __attribute__((aligned(16))) u16 As[32 * 32];    // 2 KB
  __shared__ __attribute__((aligned(16))) u16 Bs[128 * 32];   // 8 KB
  __shared__ float4 mt[3][32][16];                            // 24 KB

  const int tid = threadIdx.x;
  const int w = tid >> 6, l = tid & 63;
  const int lr = l & 15, g = l >> 4;
  const int bg = (blockIdx.x & 7) * 128 + (blockIdx.x >> 3);  // XCD swizzle
  const int m0 = bg * 32;

  float d0[2][4], d1[2][4];
  int i0[2][4], i1[2][4];
#pragma unroll
  for (int mr = 0; mr < 2; ++mr)
#pragma unroll
    for (int q = 0; q < 4; ++q) {
      d0[mr][q] = 3.4e38f; d1[mr][q] = 3.4e38f;
      i0[mr][q] = 0; i1[mr][q] = 0;
    }

  for (int chunk = 0; chunk < KCB / 128; ++chunk) {
    const int cbase = chunk * 128;
    f32x4 acc[2][2];
#pragma unroll
    for (int mr = 0; mr < 2; ++mr)
#pragma unroll
      for (int nr = 0; nr < 2; ++nr) acc[mr][nr] = (f32x4)0.0f;

    for (int ks = 0; ks < HID / 32; ++ks) {
      const int k0 = ks * 32;
      __syncthreads();
      if (w < 2)
        stage16(Ahi, m0 + w * 16, w * 16, k0, As + w * 16 * 32, l, HID);
      stage16(Bhi, cbase + w * 16, w * 16, k0, Bs + w * 16 * 32, l, HID);
      stage16(Bhi, cbase + (w + 4) * 16, (w + 4) * 16, k0, Bs + (w + 4) * 16 * 32, l, HID);
      __syncthreads();

      f16x8 ah[2], bh[2];
#pragma unroll
      for (int mr = 0; mr < 2; ++mr) {
        const int ra = mr * 16 + lr;
        ah[mr] = *(const f16x8*)(As + ra * 32 + (g ^ SWZ(ra)) * 8);
      }
#pragma unroll
      for (int nr = 0; nr < 2; ++nr) {
        const int rb = w * 32 + nr * 16 + lr;
        bh[nr] = *(const f16x8*)(Bs + rb * 32 + (g ^ SWZ(rb)) * 8);
      }
#pragma unroll
      for (int mr = 0; mr < 2; ++mr)
#pragma unroll
        for (int nr = 0; nr < 2; ++nr)
          acc[mr][nr] = __builtin_amdgcn_mfma_f32_16x16x32_f16(
              ah[mr], bh[nr], acc[mr][nr], 0, 0, 0);
    }

    // top-2 insert per (mr,q) token-slot
#pragma unroll
    for (int nr = 0; nr < 2; ++nr) {
      const int code = cbase + w * 32 + nr * 16 + lr;
      const float cf = cnf[code];
#pragma unroll
      for (int mr = 0; mr < 2; ++mr) {
#pragma unroll
        for (int q = 0; q < 4; ++q) {
          float d = fmaf(-2.0f, acc[mr][nr][q], cf);
          if (d < d1[mr][q]) {
            if (d < d0[mr][q]) {
              d1[mr][q] = d0[mr][q]; i1[mr][q] = i0[mr][q];
              d0[mr][q] = d; i0[mr][q] = code;
            } else {
              d1[mr][q] = d; i1[mr][q] = code;
            }
          }
        }
      }
    }
  }

  // cross-wave merge: waves 1..3 publish, wave 0 merges 8 entries -> top-2
  __syncthreads();
  if (w >= 1) {
#pragma unroll
    for (int mr = 0; mr < 2; ++mr)
#pragma unroll
      for (int q = 0; q < 4; ++q) {
        const int tl = mr * 16 + g * 4 + q;
        float4 e;
        e.x = d0[mr][q]; e.y = (float)i0[mr][q];
        e.z = d1[mr][q]; e.w = (float)i1[mr][q];
        mt[w - 1][tl][lr] = e;
      }
  }
  __syncthreads();
  if (w == 0) {
#pragma unroll
    for (int mr = 0; mr < 2; ++mr)
#pragma unroll
      for (int q = 0; q < 4; ++q) {
        const int tl = mr * 16 + g * 4 + q;
        float e0d = d0[mr][q], e1d = d1[mr][q];
        int e0i = i0[mr][q], e1i = i1[mr][q];
#pragma unroll
        for (int j = 0; j < 3; ++j) {
          float4 o = mt[j][tl][lr];
          int oi0 = (int)o.y, oi1 = (int)o.w;
          if (o.x < e1d) {
            if (o.x < e0d) { e1d = e0d; e1i = e0i; e0d = o.x; e0i = oi0; }
            else { e1d = o.x; e1i = oi0; }
          }
          if (o.z < e1d) {
            if (o.z < e0d) { e1d = e0d; e1i = e0i; e0d = o.z; e0i = oi1; }
            else { e1d = o.z; e1i = oi1; }
          }
        }
        float4 out;
        out.x = e0d; out.y = (float)e0i; out.z = e1d; out.w = (float)e1i;
        *(float4*)(cand + ((size_t)(m0 + tl) * 32 + lr * 2) * 2) = out;
      }
  }
}

// ---------------------------------------------------------------------------
// PASS 2 (unchanged, r13-proven): min of pass-1 d; entries within MARGIN
// recomputed exactly: d = cn - 2*dot(r, cb) in f64 (r from splits, cb f32).
// f64 compare + smallest-index tie-break.
// ---------------------------------------------------------------------------
__global__ __launch_bounds__(256) void rvq_argmin_p2(
    const float* __restrict__ cand,
    const u16* __restrict__ rhi, const u16* __restrict__ rlo,
    const float* __restrict__ cb, const double* __restrict__ cn,
    int* __restrict__ idxbuf, float* __restrict__ idxout) {
  const int tid = threadIdx.x;
  const int wv = tid >> 6, l = tid & 63;
  const int t = blockIdx.x * 4 + wv;

  float ed = 3.4e38f;
  int ei = 0;
  if (l < 32) {
    float2 e = *(const float2*)(cand + ((size_t)t * 32 + l) * 2);
    ed = e.x;
    ei = (int)e.y;
  }
  float dmin = ed;
#pragma unroll
  for (int off = 32; off > 0; off >>= 1)
    dmin = fminf(dmin, __shfl_xor(dmin, off, 64));
  const bool flag = (l < 32) && (ed <= dmin + MARGIN);
  unsigned long long mask = __ballot(flag);

  const ushort4* hp = (const ushort4*)(rhi + (size_t)t * HID + l * 8);
  const ushort4* lp = (const ushort4*)(rlo + (size_t)t * HID + l * 8);
  ushort4 h0 = hp[0], h1 = hp[1], l0 = lp[0], l1 = lp[1];
  float r[8];
  r[0] = h_bits2f(h0.x) + h_bits2f(l0.x) * (1.0f / 2048.0f);
  r[1] = h_bits2f(h0.y) + h_bits2f(l0.y) * (1.0f / 2048.0f);
  r[2] = h_bits2f(h0.z) + h_bits2f(l0.z) * (1.0f / 2048.0f);
  r[3] = h_bits2f(h0.w) + h_bits2f(l0.w) * (1.0f / 2048.0f);
  r[4] = h_bits2f(h1.x) + h_bits2f(l1.x) * (1.0f / 2048.0f);
  r[5] = h_bits2f(h1.y) + h_bits2f(l1.y) * (1.0f / 2048.0f);
  r[6] = h_bits2f(h1.z) + h_bits2f(l1.z) * (1.0f / 2048.0f);
  r[7] = h_bits2f(h1.w) + h_bits2f(l1.w) * (1.0f / 2048.0f);

  double bd = 1e300;
  int bi = 0;
  while (mask) {
    const int src = __builtin_ctzll(mask);
    mask &= mask - 1;
    const int idx = __shfl(ei, src, 64);
    const float4* crow = (const float4*)(cb + (size_t)idx * HID + l * 8);
    float4 c0 = crow[0], c1 = crow[1];
    double s = (double)r[0] * (double)c0.x + (double)r[1] * (double)c0.y
             + (double)r[2] * (double)c0.z + (double)r[3] * (double)c0.w
             + (double)r[4] * (double)c1.x + (double)r[5] * (double)c1.y
             + (double)r[6] * (double)c1.z + (double)r[7] * (double)c1.w;
#pragma unroll
    for (int off = 32; off > 0; off >>= 1) s += __shfl_xor(s, off, 64);
    const double d = cn[idx] - 2.0 * s;
    if (d < bd || (d == bd && idx < bi)) { bd = d; bi = idx; }
  }
  if (l == 0) {
    idxbuf[t] = bi;
    idxout[t] = (float)bi;
  }
}

// ---------------------------------------------------------------------------
// Gather sel; quant += sel; resid(split) -= sel.
// FIRST: quant starts at 0. LAST: splits <- fsplit(quant) for the decoder.
// ---------------------------------------------------------------------------
template <bool FIRST, bool LAST>
__global__ __launch_bounds__(256) void rvq_update(
    const float* __restrict__ cb, const int* __restrict__ idxbuf,
    float* __restrict__ quant, u16* __restrict__ rhi, u16* __restrict__ rlo) {
  const size_t gid = (size_t)blockIdx.x * blockDim.x + threadIdx.x;
  const int t = (int)(gid >> 7);
  const int q4 = (int)(gid & 127);
  const int idx = idxbuf[t];
  const float4 c = *((const float4*)(cb + (size_t)idx * HID) + q4);
  float4* qp = (float4*)(quant + (size_t)t * HID) + q4;
  float cc[4] = {c.x, c.y, c.z, c.w};
  float qn[4];
  if (FIRST) {
    qn[0] = cc[0]; qn[1] = cc[1]; qn[2] = cc[2]; qn[3] = cc[3];
  } else {
    float4 qv = *qp;
    qn[0] = qv.x + cc[0]; qn[1] = qv.y + cc[1];
    qn[2] = qv.z + cc[2]; qn[3] = qv.w + cc[3];
  }
  ushort4* hp = (ushort4*)(rhi + (size_t)t * HID) + q4;
  ushort4* lp = (ushort4*)(rlo + (size_t)t * HID) + q4;
  ushort4 h4 = *hp, l4 = *lp;
  u16 hs[4] = {h4.x, h4.y, h4.z, h4.w}, ls[4] = {l4.x, l4.y, l4.z, l4.w};
#pragma unroll
  for (int j = 0; j < 4; ++j) {
    if (LAST) {
      fsplit(qn[j], hs[j], ls[j]);
    } else {
      float r = h_bits2f(hs[j]) + h_bits2f(ls[j]) * (1.0f / 2048.0f) - cc[j];
      fsplit(r, hs[j], ls[j]);
    }
  }
  float4 qo;
  qo.x = qn[0]; qo.y = qn[1]; qo.z = qn[2]; qo.w = qn[3];
  *qp = qo;
  h4.x = hs[0]; h4.y = hs[1]; h4.z = hs[2]; h4.w = hs[3];
  l4.x = ls[0]; l4.y = ls[1]; l4.z = ls[2]; l4.w = ls[3];
  *hp = h4;
  *lp = l4;
}

// ---------------------------------------------------------------------------
extern "C" void kernel_launch(void* const* d_in, const int* in_sizes, int n_in,
                              void* d_out, int out_size, void* d_ws, size_t ws_size,
                              hipStream_t stream) {
  const float* x      = (const float*)d_in[0];
  const float* enc_w1 = (const float*)d_in[1];
  const float* enc_b1 = (const float*)d_in[2];
  const float* enc_w2 = (const float*)d_in[3];
  const float* enc_b2 = (const float*)d_in[4];
  const float* dec_w1 = (const float*)d_in[5];
  const float* dec_b1 = (const float*)d_in[6];
  const float* dec_w2 = (const float*)d_in[7];
  const float* dec_b2 = (const float*)d_in[8];
  const float* cbs    = (const float*)d_in[9];

  float* quant  = (float*)d_out;
  float* idxout = quant + (size_t)N_TOK * HID;
  float* recon  = idxout + (size_t)NCB * N_TOK;

  // workspace (~94.5 MB)
  char* wsp = (char*)d_ws;
  u16* rhi = (u16*)wsp;       wsp += (size_t)N_TOK * HID * 2;
  u16* rlo = (u16*)wsp;       wsp += (size_t)N_TOK * HID * 2;
  u16* whi = (u16*)wsp;       wsp += (size_t)2560 * 1024 * 2;
  u16* wlo = (u16*)wsp;       wsp += (size_t)2560 * 1024 * 2;
  char* h1region = wsp;       wsp += (size_t)CHUNK_E * H2 * 4;
  int* idxbuf = (int*)wsp;    wsp += (size_t)NCB * N_TOK * 4;
  double* cn = (double*)wsp;  wsp += (size_t)NCB * KCB * 8;
  float* cnf = (float*)wsp;   wsp += (size_t)NCB * KCB * 4;

  u16* dw1Thi = whi;              u16* dw1Tlo = wlo;
  u16* dw2Thi = whi + 524288;     u16* dw2Tlo = wlo + 524288;

  float* h1f  = (float*)h1region;                     // enc hidden (f32)
  u16*   h1hi = (u16*)h1region;                       // dec hidden (f16)
  u16*   cbshi = (u16*)h1region;                      // RVQ: hi-plane cb split
  float* cand = (float*)(h1region + (size_t)KCB * HID * 2);  // 8.39 MB cand buf

  wtsplit<<<dim3(H2 / 32, HID / 32), 256, 0, stream>>>(dec_w1, dw1Thi, dw1Tlo, HID, H2);
  wtsplit<<<dim3(DIN / 32, H2 / 32), 256, 0, stream>>>(dec_w2, dw2Thi, dw2Tlo, H2, DIN);
  cnorm_kernel<<<NCB * KCB / 4, 256, 0, stream>>>(cbs, cn, cnf);

  // encoder: fp32, bit-exact k-order (index-critical)
  for (int c = 0; c < N_TOK / CHUNK_E; ++c) {
    gemm_f32ek<true, false><<<dim3(H2 / 64, CHUNK_E / 64), 256, 0, stream>>>(
        x + (size_t)c * CHUNK_E * DIN, enc_w1, enc_b1, h1f, nullptr, nullptr,
        CHUNK_E, DIN, H2);
    gemm_f32ek<false, true><<<dim3(HID / 64, CHUNK_E / 64), 256, 0, stream>>>(
        h1f, enc_w2, enc_b2, nullptr,
        rhi + (size_t)c * CHUNK_E * HID, rlo + (size_t)c * CHUNK_E * HID,
        CHUNK_E, H2, HID);
  }

  // RVQ stages: pass-1 screen (hi*hi) -> pass-2 exact refine -> update
  for (int s = 0; s < NCB; ++s) {
    const float* cb = cbs + (size_t)s * KCB * HID;
    cbsplit_kernel<<<(KCB * HID / 4) / 256, 256, 0, stream>>>(cb, cbshi);
    rvq_argmin_p1<<<N_TOK / 32, 256, 0, stream>>>(
        rhi, cbshi, cnf + (size_t)s * KCB, cand);
    rvq_argmin_p2<<<N_TOK / 4, 256, 0, stream>>>(
        cand, rhi, rlo, cb, cn + (size_t)s * KCB,
        idxbuf + (size_t)s * N_TOK, idxout + (size_t)s * N_TOK);
    if (s == 0)
      rvq_update<true, false><<<(N_TOK * 128) / 256, 256, 0, stream>>>(
          cb, idxbuf + (size_t)s * N_TOK, quant, rhi, rlo);
    else if (s < NCB - 1)
      rvq_update<false, false><<<(N_TOK * 128) / 256, 256, 0, stream>>>(
          cb, idxbuf + (size_t)s * N_TOK, quant, rhi, rlo);
    else
      rvq_update<false, true><<<(N_TOK * 128) / 256, 256, 0, stream>>>(
          cb, idxbuf + (size_t)s * N_TOK, quant, rhi, rlo);
  }

  // decoder: single-product f16 MFMA
  for (int c = 0; c < N_TOK / CHUNK_D; ++c) {
    gemm_mfma_f16<true, true><<<dim3(H2 / 128, CHUNK_D / 64), 256, 0, stream>>>(
        rhi + (size_t)c * CHUNK_D * HID, dw1Thi, dec_b1,
        nullptr, h1hi, CHUNK_D, HID, H2);
    gemm_mfma_f16<false, false><<<dim3(DIN / 128, CHUNK_D / 64), 256, 0, stream>>>(
        h1hi, dw2Thi, dec_b2,
        recon + (size_t)c * CHUNK_D * DIN, nullptr, CHUNK_D, H2, DIN);
  }
}

// Round 15
// 2807.734 us; speedup vs baseline: 1.1381x; 1.1381x over previous
//
#include <hip/hip_runtime.h>

#define N_TOK 32768
#define DIN   1024
#define HID   512
#define H2    1024
#define KCB   4096
#define NCB   3
#define CHUNK_E 4096
#define CHUNK_D 8192
#define MARGIN 0.25f   // pass-1 candidate window; ~140 sigma of hi*hi d error

typedef _Float16 f16x8 __attribute__((ext_vector_type(8)));
typedef float f32x4 __attribute__((ext_vector_type(4)));
typedef unsigned short u16;

__device__ inline u16 f2h_bits(float v) {
  union { _Float16 f; u16 u; } cv;
  cv.f = (_Float16)v;
  return cv.u;
}
__device__ inline float h_bits2f(u16 u) {
  union { _Float16 f; u16 u; } cv;
  cv.u = u;
  return (float)cv.f;
}
// split v = hi + (lo/2048); lo stored pre-scaled by 2048 (avoids f16 subnormals)
__device__ inline void fsplit(float v, u16& hi, u16& lo) {
  _Float16 h = (_Float16)v;
  float hf = (float)h;
  union { _Float16 f; u16 u; } ch; ch.f = h; hi = ch.u;
  lo = f2h_bits((v - hf) * 2048.0f);
}

#define SWZ(r) (((r) >> 1) & 3)

__device__ inline void stage16(const u16* gplane, int growbase, int lrowbase,
                               int k0, u16* ldsbase, int l, int stride) {
  const int rp = l >> 2, s = l & 3;
  const int sp = s ^ SWZ(lrowbase + rp);
  const u16* src = gplane + (size_t)(growbase + rp) * stride + k0 + sp * 8;
  __builtin_amdgcn_global_load_lds(
      (const __attribute__((address_space(1))) void*)src,
      (__attribute__((address_space(3))) void*)ldsbase, 16, 0, 0);
}

// ---------------------------------------------------------------------------
// fp32 GEMM, 64x64 tile, k-major aligned LDS — index-critical (r10-proven).
// BIT-EXACT k-order. DO NOT reorder k.
// ---------------------------------------------------------------------------
template <bool RELU, bool SPLIT>
__global__ __launch_bounds__(256) void gemm_f32ek(
    const float* __restrict__ A, const float* __restrict__ B,
    const float* __restrict__ bias, float* __restrict__ C,
    u16* __restrict__ Chi, u16* __restrict__ Clo,
    int M, int K, int Nn) {
  __shared__ float As[16][68];
  __shared__ float Bs[16][68];
  const int tid = threadIdx.x;
  const int tx = tid & 15, ty = tid >> 4;
  const int tx4 = tx * 4, ty4 = ty * 4;
  const int m0 = blockIdx.y * 64, n0 = blockIdx.x * 64;

  const int ar = tid >> 2;
  const int aq = (tid & 3) * 4;
  const int bk = tid >> 4;
  const int bn = (tid & 15) * 4;

  float acc[4][4] = {};

  for (int k0 = 0; k0 < K; k0 += 16) {
    float4 av = *(const float4*)(A + (size_t)(m0 + ar) * K + k0 + aq);
    As[aq + 0][ar] = av.x; As[aq + 1][ar] = av.y;
    As[aq + 2][ar] = av.z; As[aq + 3][ar] = av.w;
    *(float4*)(&Bs[bk][bn]) = *(const float4*)(B + (size_t)(k0 + bk) * Nn + n0 + bn);
    __syncthreads();
#pragma unroll
    for (int kk = 0; kk < 16; ++kk) {
      float4 a4 = *(float4*)(&As[kk][ty4]);
      float4 b4 = *(float4*)(&Bs[kk][tx4]);
      float a[4] = {a4.x, a4.y, a4.z, a4.w};
      float bv[4] = {b4.x, b4.y, b4.z, b4.w};
#pragma unroll
      for (int i = 0; i < 4; ++i)
#pragma unroll
        for (int j = 0; j < 4; ++j) acc[i][j] = fmaf(a[i], bv[j], acc[i][j]);
    }
    __syncthreads();
  }

  float bb[4];
#pragma unroll
  for (int j = 0; j < 4; ++j) bb[j] = bias[n0 + tx4 + j];
#pragma unroll
  for (int i = 0; i < 4; ++i) {
    const size_t row = (size_t)(m0 + ty4 + i);
    if (SPLIT) {
      ushort4 h4, l4;
      u16 hs[4], ls[4];
#pragma unroll
      for (int j = 0; j < 4; ++j) {
        float v = acc[i][j] + bb[j];
        if (RELU) v = v > 0.0f ? v : 0.0f;
        fsplit(v, hs[j], ls[j]);
      }
      h4.x = hs[0]; h4.y = hs[1]; h4.z = hs[2]; h4.w = hs[3];
      l4.x = ls[0]; l4.y = ls[1]; l4.z = ls[2]; l4.w = ls[3];
      *(ushort4*)(&Chi[row * Nn + n0 + tx4]) = h4;
      *(ushort4*)(&Clo[row * Nn + n0 + tx4]) = l4;
    } else {
      float4 o;
      float vv[4];
#pragma unroll
      for (int j = 0; j < 4; ++j) {
        float v = acc[i][j] + bb[j];
        if (RELU) v = v > 0.0f ? v : 0.0f;
        vv[j] = v;
      }
      o.x = vv[0]; o.y = vv[1]; o.z = vv[2]; o.w = vv[3];
      *(float4*)(&C[row * Nn + n0 + tx4]) = o;
    }
  }
}

// ---------------------------------------------------------------------------
// Single-product f16 MFMA GEMM (decoder only).
// ---------------------------------------------------------------------------
template <bool RELU, bool F16OUT>
__global__ __launch_bounds__(256) void gemm_mfma_f16(
    const u16* __restrict__ Ahi, const u16* __restrict__ BThi,
    const float* __restrict__ bias,
    float* __restrict__ C, u16* __restrict__ Chi,
    int M, int K, int Nn) {
  __shared__ __attribute__((aligned(16))) u16 As[64 * 32];
  __shared__ __attribute__((aligned(16))) u16 Bs[128 * 32];
  const int tid = threadIdx.x;
  const int w = tid >> 6, l = tid & 63;
  const int wr = w >> 1, wc = w & 1;
  const int lr = l & 15, g = l >> 4;
  const int m0 = blockIdx.y * 64, n0 = blockIdx.x * 128;

  f32x4 acc[2][4];
#pragma unroll
  for (int mr = 0; mr < 2; ++mr)
#pragma unroll
    for (int nr = 0; nr < 4; ++nr) acc[mr][nr] = (f32x4)0.0f;

  for (int ks = 0; ks < K / 32; ++ks) {
    const int k0 = ks * 32;
    __syncthreads();
    stage16(Ahi, m0 + w * 16, w * 16, k0, As + w * 16 * 32, l, K);
    stage16(BThi, n0 + w * 16, w * 16, k0, Bs + w * 16 * 32, l, K);
    stage16(BThi, n0 + (w + 4) * 16, (w + 4) * 16, k0, Bs + (w + 4) * 16 * 32, l, K);
    __syncthreads();

    f16x8 ah[2], bh[4];
#pragma unroll
    for (int mr = 0; mr < 2; ++mr) {
      const int ra = wr * 32 + mr * 16 + lr;
      ah[mr] = *(const f16x8*)(As + ra * 32 + (g ^ SWZ(ra)) * 8);
    }
#pragma unroll
    for (int nr = 0; nr < 4; ++nr) {
      const int rb = wc * 64 + nr * 16 + lr;
      bh[nr] = *(const f16x8*)(Bs + rb * 32 + (g ^ SWZ(rb)) * 8);
    }
#pragma unroll
    for (int mr = 0; mr < 2; ++mr)
#pragma unroll
      for (int nr = 0; nr < 4; ++nr)
        acc[mr][nr] = __builtin_amdgcn_mfma_f32_16x16x32_f16(
            ah[mr], bh[nr], acc[mr][nr], 0, 0, 0);
  }

#pragma unroll
  for (int nr = 0; nr < 4; ++nr) {
    const int col = n0 + wc * 64 + nr * 16 + lr;
    const float bb = bias[col];
#pragma unroll
    for (int mr = 0; mr < 2; ++mr) {
#pragma unroll
      for (int q = 0; q < 4; ++q) {
        const int row = m0 + wr * 32 + mr * 16 + g * 4 + q;
        float v = acc[mr][nr][q] + bb;
        if (RELU) v = v > 0.0f ? v : 0.0f;
        if (F16OUT) Chi[(size_t)row * Nn + col] = f2h_bits(v);
        else C[(size_t)row * Nn + col] = v;
      }
    }
  }
}

// ---------------------------------------------------------------------------
__global__ __launch_bounds__(256) void wtsplit(
    const float* __restrict__ W, u16* __restrict__ Thi, u16* __restrict__ Tlo,
    int K, int N) {
  __shared__ float tile[32][33];
  const int k0 = blockIdx.y * 32, n0 = blockIdx.x * 32;
  const int c = threadIdx.x & 31, r8 = threadIdx.x >> 5;
#pragma unroll
  for (int p = 0; p < 4; ++p) {
    const int r = r8 + p * 8;
    tile[r][c] = W[(size_t)(k0 + r) * N + n0 + c];
  }
  __syncthreads();
#pragma unroll
  for (int p = 0; p < 4; ++p) {
    const int r = r8 + p * 8;
    float v = tile[c][r];
    u16 hh, ll;
    fsplit(v, hh, ll);
    Thi[(size_t)(n0 + r) * K + k0 + c] = hh;
    Tlo[(size_t)(n0 + r) * K + k0 + c] = ll;
  }
}

// ---------------------------------------------------------------------------
// Codebook split: only HI plane needed (pass-1 hi*hi; pass-2 uses f32 cb).
// ---------------------------------------------------------------------------
__global__ __launch_bounds__(256) void cbsplit_kernel(
    const float* __restrict__ cb, u16* __restrict__ hi) {
  const size_t i4 = (size_t)blockIdx.x * 256 + threadIdx.x;
  float4 v = *(const float4*)(cb + i4 * 4);
  ushort4 h4;
  u16 dummy;
  fsplit(v.x, h4.x, dummy);
  fsplit(v.y, h4.y, dummy);
  fsplit(v.z, h4.z, dummy);
  fsplit(v.w, h4.w, dummy);
  *(ushort4*)(hi + i4 * 4) = h4;
}

// ---------------------------------------------------------------------------
// Codebook squared norms: f64 (exact, for pass-2) + f32 (for pass-1).
// ---------------------------------------------------------------------------
__global__ __launch_bounds__(256) void cnorm_kernel(
    const float* __restrict__ cb, double* __restrict__ cn,
    float* __restrict__ cnf) {
  const int w = blockIdx.x * 4 + (threadIdx.x >> 6);
  const int lane = threadIdx.x & 63;
  const float* row = cb + (size_t)w * HID;
  double s = 0.0;
  for (int h = lane; h < HID; h += 64) {
    double v = (double)row[h];
    s += v * v;
  }
#pragma unroll
  for (int off = 32; off > 0; off >>= 1) s += __shfl_down(s, off, 64);
  if (lane == 0) { cn[w] = s; cnf[w] = (float)s; }
}

// ---------------------------------------------------------------------------
// PASS 1 (screen only — exactness lives in pass 2). r13-PROVEN block body
// (64 tokens, 4 waves, 8 MFMA/wave/barrier) — UNCHANGED INTERNALS.
// Occupancy fix via grid only: blockIdx.y ∈ {0,1} splits the code range
// (16 chunks each) -> 1024 blocks = 4 blocks/CU (fits: 80 VGPR -> 6 w/SIMD,
// 28 KB LDS -> 5 blocks). r14's 32-token retile halved per-barrier MFMA
// density and regressed — grid was the lever, not block shape.
// cand[t][64]: split s writes entries [s*32, s*32+32).
// ---------------------------------------------------------------------------
__global__ __launch_bounds__(256) void rvq_argmin_p1(
    const u16* __restrict__ Ahi, const u16* __restrict__ Bhi,
    const float* __restrict__ cnf, float* __restrict__ cand) {
  __shared__ __attribute__((aligned(16))) u16 As[64 * 32];    // 4 KB
  __shared__ __attribute__((aligned(16))) u16 Bs[128 * 32];   // 8 KB
  __shared__ float4 mt[64][16];                               // 16 KB

  const int tid = threadIdx.x;
  const int w = tid >> 6, l = tid & 63;
  const int wr = w >> 1, wc = w & 1;
  const int lr = l & 15, g = l >> 4;
  const int bg = (blockIdx.x & 7) * 64 + (blockIdx.x >> 3);
  const int m0 = bg * 64;
  const int split = blockIdx.y;

  float d0[2][4], d1[2][4];
  int i0[2][4], i1[2][4];
#pragma unroll
  for (int mr = 0; mr < 2; ++mr)
#pragma unroll
    for (int q = 0; q < 4; ++q) {
      d0[mr][q] = 3.4e38f; d1[mr][q] = 3.4e38f;
      i0[mr][q] = 0; i1[mr][q] = 0;
    }

  for (int chunk = split * 16; chunk < split * 16 + 16; ++chunk) {
    const int cbase = chunk * 128;
    f32x4 acc[2][4];
#pragma unroll
    for (int mr = 0; mr < 2; ++mr)
#pragma unroll
      for (int nr = 0; nr < 4; ++nr) acc[mr][nr] = (f32x4)0.0f;

    for (int ks = 0; ks < HID / 32; ++ks) {
      const int k0 = ks * 32;
      __syncthreads();
      stage16(Ahi, m0 + w * 16, w * 16, k0, As + w * 16 * 32, l, HID);
      stage16(Bhi, cbase + w * 16, w * 16, k0, Bs + w * 16 * 32, l, HID);
      stage16(Bhi, cbase + (w + 4) * 16, (w + 4) * 16, k0, Bs + (w + 4) * 16 * 32, l, HID);
      __syncthreads();

      f16x8 ah[2], bh[4];
#pragma unroll
      for (int mr = 0; mr < 2; ++mr) {
        const int ra = wr * 32 + mr * 16 + lr;
        ah[mr] = *(const f16x8*)(As + ra * 32 + (g ^ SWZ(ra)) * 8);
      }
#pragma unroll
      for (int nr = 0; nr < 4; ++nr) {
        const int rb = wc * 64 + nr * 16 + lr;
        bh[nr] = *(const f16x8*)(Bs + rb * 32 + (g ^ SWZ(rb)) * 8);
      }
#pragma unroll
      for (int mr = 0; mr < 2; ++mr)
#pragma unroll
        for (int nr = 0; nr < 4; ++nr)
          acc[mr][nr] = __builtin_amdgcn_mfma_f32_16x16x32_f16(
              ah[mr], bh[nr], acc[mr][nr], 0, 0, 0);
    }

    // f32 epilogue: top-2 insert per token-slot
#pragma unroll
    for (int nr = 0; nr < 4; ++nr) {
      const int code = cbase + wc * 64 + nr * 16 + lr;
      const float cf = cnf[code];
#pragma unroll
      for (int mr = 0; mr < 2; ++mr) {
#pragma unroll
        for (int q = 0; q < 4; ++q) {
          float d = fmaf(-2.0f, acc[mr][nr][q], cf);
          if (d < d1[mr][q]) {
            if (d < d0[mr][q]) {
              d1[mr][q] = d0[mr][q]; i1[mr][q] = i0[mr][q];
              d0[mr][q] = d; i0[mr][q] = code;
            } else {
              d1[mr][q] = d; i1[mr][q] = code;
            }
          }
        }
      }
    }
  }

  // merge wc=1 into wc=0 via LDS, write 2 entries per (token, lr)
  __syncthreads();
  if (wc == 1) {
#pragma unroll
    for (int mr = 0; mr < 2; ++mr)
#pragma unroll
      for (int q = 0; q < 4; ++q) {
        const int tl = wr * 32 + mr * 16 + g * 4 + q;
        float4 e;
        e.x = d0[mr][q]; e.y = (float)i0[mr][q];
        e.z = d1[mr][q]; e.w = (float)i1[mr][q];
        mt[tl][lr] = e;
      }
  }
  __syncthreads();
  if (wc == 0) {
#pragma unroll
    for (int mr = 0; mr < 2; ++mr)
#pragma unroll
      for (int q = 0; q < 4; ++q) {
        const int tl = wr * 32 + mr * 16 + g * 4 + q;
        float4 o = mt[tl][lr];
        float e0d = d0[mr][q], e1d = d1[mr][q];
        int e0i = i0[mr][q], e1i = i1[mr][q];
        int oi0 = (int)o.y, oi1 = (int)o.w;
        if (o.x < e1d) {
          if (o.x < e0d) { e1d = e0d; e1i = e0i; e0d = o.x; e0i = oi0; }
          else { e1d = o.x; e1i = oi0; }
        }
        if (o.z < e1d) {
          if (o.z < e0d) { e1d = e0d; e1i = e0i; e0d = o.z; e0i = oi1; }
          else { e1d = o.z; e1i = oi1; }
        }
        float4 out;
        out.x = e0d; out.y = (float)e0i; out.z = e1d; out.w = (float)e1i;
        *(float4*)(cand + ((size_t)(m0 + tl) * 64 + split * 32 + lr * 2) * 2) = out;
      }
  }
}

// ---------------------------------------------------------------------------
// PASS 2 (decision path unchanged from r13-proven): 64 candidate entries
// (one per lane); min pass-1 d; entries within MARGIN recomputed exactly:
// d = cn - 2*dot(r, cb) in f64. f64 compare + smallest-index tie-break.
// ---------------------------------------------------------------------------
__global__ __launch_bounds__(256) void rvq_argmin_p2(
    const float* __restrict__ cand,
    const u16* __restrict__ rhi, const u16* __restrict__ rlo,
    const float* __restrict__ cb, const double* __restrict__ cn,
    int* __restrict__ idxbuf, float* __restrict__ idxout) {
  const int tid = threadIdx.x;
  const int wv = tid >> 6, l = tid & 63;
  const int t = blockIdx.x * 4 + wv;

  float2 e = *(const float2*)(cand + ((size_t)t * 64 + l) * 2);
  float ed = e.x;
  int ei = (int)e.y;
  float dmin = ed;
#pragma unroll
  for (int off = 32; off > 0; off >>= 1)
    dmin = fminf(dmin, __shfl_xor(dmin, off, 64));
  const bool flag = (ed <= dmin + MARGIN);
  unsigned long long mask = __ballot(flag);

  const ushort4* hp = (const ushort4*)(rhi + (size_t)t * HID + l * 8);
  const ushort4* lp = (const ushort4*)(rlo + (size_t)t * HID + l * 8);
  ushort4 h0 = hp[0], h1 = hp[1], l0 = lp[0], l1 = lp[1];
  float r[8];
  r[0] = h_bits2f(h0.x) + h_bits2f(l0.x) * (1.0f / 2048.0f);
  r[1] = h_bits2f(h0.y) + h_bits2f(l0.y) * (1.0f / 2048.0f);
  r[2] = h_bits2f(h0.z) + h_bits2f(l0.z) * (1.0f / 2048.0f);
  r[3] = h_bits2f(h0.w) + h_bits2f(l0.w) * (1.0f / 2048.0f);
  r[4] = h_bits2f(h1.x) + h_bits2f(l1.x) * (1.0f / 2048.0f);
  r[5] = h_bits2f(h1.y) + h_bits2f(l1.y) * (1.0f / 2048.0f);
  r[6] = h_bits2f(h1.z) + h_bits2f(l1.z) * (1.0f / 2048.0f);
  r[7] = h_bits2f(h1.w) + h_bits2f(l1.w) * (1.0f / 2048.0f);

  double bd = 1e300;
  int bi = 0;
  while (mask) {
    const int src = __builtin_ctzll(mask);
    mask &= mask - 1;
    const int idx = __shfl(ei, src, 64);
    const float4* crow = (const float4*)(cb + (size_t)idx * HID + l * 8);
    float4 c0 = crow[0], c1 = crow[1];
    double s = (double)r[0] * (double)c0.x + (double)r[1] * (double)c0.y
             + (double)r[2] * (double)c0.z + (double)r[3] * (double)c0.w
             + (double)r[4] * (double)c1.x + (double)r[5] * (double)c1.y
             + (double)r[6] * (double)c1.z + (double)r[7] * (double)c1.w;
#pragma unroll
    for (int off = 32; off > 0; off >>= 1) s += __shfl_xor(s, off, 64);
    const double d = cn[idx] - 2.0 * s;
    if (d < bd || (d == bd && idx < bi)) { bd = d; bi = idx; }
  }
  if (l == 0) {
    idxbuf[t] = bi;
    idxout[t] = (float)bi;
  }
}

// ---------------------------------------------------------------------------
// Gather sel; quant += sel; resid(split) -= sel.
// FIRST: quant starts at 0. LAST: splits <- fsplit(quant) for the decoder.
// ---------------------------------------------------------------------------
template <bool FIRST, bool LAST>
__global__ __launch_bounds__(256) void rvq_update(
    const float* __restrict__ cb, const int* __restrict__ idxbuf,
    float* __restrict__ quant, u16* __restrict__ rhi, u16* __restrict__ rlo) {
  const size_t gid = (size_t)blockIdx.x * blockDim.x + threadIdx.x;
  const int t = (int)(gid >> 7);
  const int q4 = (int)(gid & 127);
  const int idx = idxbuf[t];
  const float4 c = *((const float4*)(cb + (size_t)idx * HID) + q4);
  float4* qp = (float4*)(quant + (size_t)t * HID) + q4;
  float cc[4] = {c.x, c.y, c.z, c.w};
  float qn[4];
  if (FIRST) {
    qn[0] = cc[0]; qn[1] = cc[1]; qn[2] = cc[2]; qn[3] = cc[3];
  } else {
    float4 qv = *qp;
    qn[0] = qv.x + cc[0]; qn[1] = qv.y + cc[1];
    qn[2] = qv.z + cc[2]; qn[3] = qv.w + cc[3];
  }
  ushort4* hp = (ushort4*)(rhi + (size_t)t * HID) + q4;
  ushort4* lp = (ushort4*)(rlo + (size_t)t * HID) + q4;
  ushort4 h4 = *hp, l4 = *lp;
  u16 hs[4] = {h4.x, h4.y, h4.z, h4.w}, ls[4] = {l4.x, l4.y, l4.z, l4.w};
#pragma unroll
  for (int j = 0; j < 4; ++j) {
    if (LAST) {
      fsplit(qn[j], hs[j], ls[j]);
    } else {
      float r = h_bits2f(hs[j]) + h_bits2f(ls[j]) * (1.0f / 2048.0f) - cc[j];
      fsplit(r, hs[j], ls[j]);
    }
  }
  float4 qo;
  qo.x = qn[0]; qo.y = qn[1]; qo.z = qn[2]; qo.w = qn[3];
  *qp = qo;
  h4.x = hs[0]; h4.y = hs[1]; h4.z = hs[2]; h4.w = hs[3];
  l4.x = ls[0]; l4.y = ls[1]; l4.z = ls[2]; l4.w = ls[3];
  *hp = h4;
  *lp = l4;
}

// ---------------------------------------------------------------------------
extern "C" void kernel_launch(void* const* d_in, const int* in_sizes, int n_in,
                              void* d_out, int out_size, void* d_ws, size_t ws_size,
                              hipStream_t stream) {
  const float* x      = (const float*)d_in[0];
  const float* enc_w1 = (const float*)d_in[1];
  const float* enc_b1 = (const float*)d_in[2];
  const float* enc_w2 = (const float*)d_in[3];
  const float* enc_b2 = (const float*)d_in[4];
  const float* dec_w1 = (const float*)d_in[5];
  const float* dec_b1 = (const float*)d_in[6];
  const float* dec_w2 = (const float*)d_in[7];
  const float* dec_b2 = (const float*)d_in[8];
  const float* cbs    = (const float*)d_in[9];

  float* quant  = (float*)d_out;
  float* idxout = quant + (size_t)N_TOK * HID;
  float* recon  = idxout + (size_t)NCB * N_TOK;

  // workspace (~99.1 MB; 101.15 proven safe)
  char* wsp = (char*)d_ws;
  u16* rhi = (u16*)wsp;       wsp += (size_t)N_TOK * HID * 2;       // 33.55 MB
  u16* rlo = (u16*)wsp;       wsp += (size_t)N_TOK * HID * 2;       // 33.55 MB
  u16* whi = (u16*)wsp;       wsp += (size_t)2560 * 1024 * 2;       // 5.24 MB
  u16* wlo = (u16*)wsp;       wsp += (size_t)2560 * 1024 * 2;       // 5.24 MB
  char* h1region = wsp;       wsp += (size_t)20971520;              // 20.97 MB
  int* idxbuf = (int*)wsp;    wsp += (size_t)NCB * N_TOK * 4;       // 0.39 MB
  double* cn = (double*)wsp;  wsp += (size_t)NCB * KCB * 8;         // 0.10 MB
  float* cnf = (float*)wsp;   wsp += (size_t)NCB * KCB * 4;         // 0.05 MB

  u16* dw1Thi = whi;              u16* dw1Tlo = wlo;
  u16* dw2Thi = whi + 524288;     u16* dw2Tlo = wlo + 524288;

  float* h1f  = (float*)h1region;                     // enc hidden (f32, 16.78 MB)
  u16*   h1hi = (u16*)h1region;                       // dec hidden (f16, 16 MB)
  u16*   cbshi = (u16*)h1region;                      // RVQ: hi-plane cb (4 MB)
  float* cand = (float*)(h1region + (size_t)KCB * HID * 2);  // 16.78 MB cand

  wtsplit<<<dim3(H2 / 32, HID / 32), 256, 0, stream>>>(dec_w1, dw1Thi, dw1Tlo, HID, H2);
  wtsplit<<<dim3(DIN / 32, H2 / 32), 256, 0, stream>>>(dec_w2, dw2Thi, dw2Tlo, H2, DIN);
  cnorm_kernel<<<NCB * KCB / 4, 256, 0, stream>>>(cbs, cn, cnf);

  // encoder: fp32, bit-exact k-order (index-critical)
  for (int c = 0; c < N_TOK / CHUNK_E; ++c) {
    gemm_f32ek<true, false><<<dim3(H2 / 64, CHUNK_E / 64), 256, 0, stream>>>(
        x + (size_t)c * CHUNK_E * DIN, enc_w1, enc_b1, h1f, nullptr, nullptr,
        CHUNK_E, DIN, H2);
    gemm_f32ek<false, true><<<dim3(HID / 64, CHUNK_E / 64), 256, 0, stream>>>(
        h1f, enc_w2, enc_b2, nullptr,
        rhi + (size_t)c * CHUNK_E * HID, rlo + (size_t)c * CHUNK_E * HID,
        CHUNK_E, H2, HID);
  }

  // RVQ stages: pass-1 screen (hi*hi, code-split grid) -> pass-2 exact -> update
  for (int s = 0; s < NCB; ++s) {
    const float* cb = cbs + (size_t)s * KCB * HID;
    cbsplit_kernel<<<(KCB * HID / 4) / 256, 256, 0, stream>>>(cb, cbshi);
    rvq_argmin_p1<<<dim3(N_TOK / 64, 2), 256, 0, stream>>>(
        rhi, cbshi, cnf + (size_t)s * KCB, cand);
    rvq_argmin_p2<<<N_TOK / 4, 256, 0, stream>>>(
        cand, rhi, rlo, cb, cn + (size_t)s * KCB,
        idxbuf + (size_t)s * N_TOK, idxout + (size_t)s * N_TOK);
    if (s == 0)
      rvq_update<true, false><<<(N_TOK * 128) / 256, 256, 0, stream>>>(
          cb, idxbuf + (size_t)s * N_TOK, quant, rhi, rlo);
    else if (s < NCB - 1)
      rvq_update<false, false><<<(N_TOK * 128) / 256, 256, 0, stream>>>(
          cb, idxbuf + (size_t)s * N_TOK, quant, rhi, rlo);
    else
      rvq_update<false, true><<<(N_TOK * 128) / 256, 256, 0, stream>>>(
          cb, idxbuf + (size_t)s * N_TOK, quant, rhi, rlo);
  }

  // decoder: single-product f16 MFMA
  for (int c = 0; c < N_TOK / CHUNK_D; ++c) {
    gemm_mfma_f16<true, true><<<dim3(H2 / 128, CHUNK_D / 64), 256, 0, stream>>>(
        rhi + (size_t)c * CHUNK_D * HID, dw1Thi, dec_b1,
        nullptr, h1hi, CHUNK_D, HID, H2);
    gemm_mfma_f16<false, false><<<dim3(DIN / 128, CHUNK_D / 64), 256, 0, stream>>>(
        h1hi, dw2Thi, dec_b2,
        recon + (size_t)c * CHUNK_D * DIN, nullptr, CHUNK_D, H2, DIN);
  }
}

// Round 16
// 2665.296 us; speedup vs baseline: 1.1990x; 1.0534x over previous
//
#include <hip/hip_runtime.h>

#define N_TOK 32768
#define DIN   1024
#define HID   512
#define H2    1024
#define KCB   4096
#define NCB   3
#define CHUNK_E 4096
#define CHUNK_D 8192
#define MARGIN 0.25f   // pass-1 candidate window; ~140 sigma of hi*hi d error

typedef _Float16 f16x8 __attribute__((ext_vector_type(8)));
typedef float f32x4 __attribute__((ext_vector_type(4)));
typedef unsigned short u16;

__device__ inline u16 f2h_bits(float v) {
  union { _Float16 f; u16 u; } cv;
  cv.f = (_Float16)v;
  return cv.u;
}
__device__ inline float h_bits2f(u16 u) {
  union { _Float16 f; u16 u; } cv;
  cv.u = u;
  return (float)cv.f;
}
// split v = hi + (lo/2048); lo stored pre-scaled by 2048 (avoids f16 subnormals)
__device__ inline void fsplit(float v, u16& hi, u16& lo) {
  _Float16 h = (_Float16)v;
  float hf = (float)h;
  union { _Float16 f; u16 u; } ch; ch.f = h; hi = ch.u;
  lo = f2h_bits((v - hf) * 2048.0f);
}

#define SWZ(r) (((r) >> 1) & 3)

__device__ inline void stage16(const u16* gplane, int growbase, int lrowbase,
                               int k0, u16* ldsbase, int l, int stride) {
  const int rp = l >> 2, s = l & 3;
  const int sp = s ^ SWZ(lrowbase + rp);
  const u16* src = gplane + (size_t)(growbase + rp) * stride + k0 + sp * 8;
  __builtin_amdgcn_global_load_lds(
      (const __attribute__((address_space(1))) void*)src,
      (__attribute__((address_space(3))) void*)ldsbase, 16, 0, 0);
}

// ---------------------------------------------------------------------------
// fp32 GEMM, 64x64 tile, k-major aligned LDS — index-critical (r10-proven).
// BIT-EXACT k-order. DO NOT reorder k.
// ---------------------------------------------------------------------------
template <bool RELU, bool SPLIT>
__global__ __launch_bounds__(256) void gemm_f32ek(
    const float* __restrict__ A, const float* __restrict__ B,
    const float* __restrict__ bias, float* __restrict__ C,
    u16* __restrict__ Chi, u16* __restrict__ Clo,
    int M, int K, int Nn) {
  __shared__ float As[16][68];
  __shared__ float Bs[16][68];
  const int tid = threadIdx.x;
  const int tx = tid & 15, ty = tid >> 4;
  const int tx4 = tx * 4, ty4 = ty * 4;
  const int m0 = blockIdx.y * 64, n0 = blockIdx.x * 64;

  const int ar = tid >> 2;
  const int aq = (tid & 3) * 4;
  const int bk = tid >> 4;
  const int bn = (tid & 15) * 4;

  float acc[4][4] = {};

  for (int k0 = 0; k0 < K; k0 += 16) {
    float4 av = *(const float4*)(A + (size_t)(m0 + ar) * K + k0 + aq);
    As[aq + 0][ar] = av.x; As[aq + 1][ar] = av.y;
    As[aq + 2][ar] = av.z; As[aq + 3][ar] = av.w;
    *(float4*)(&Bs[bk][bn]) = *(const float4*)(B + (size_t)(k0 + bk) * Nn + n0 + bn);
    __syncthreads();
#pragma unroll
    for (int kk = 0; kk < 16; ++kk) {
      float4 a4 = *(float4*)(&As[kk][ty4]);
      float4 b4 = *(float4*)(&Bs[kk][tx4]);
      float a[4] = {a4.x, a4.y, a4.z, a4.w};
      float bv[4] = {b4.x, b4.y, b4.z, b4.w};
#pragma unroll
      for (int i = 0; i < 4; ++i)
#pragma unroll
        for (int j = 0; j < 4; ++j) acc[i][j] = fmaf(a[i], bv[j], acc[i][j]);
    }
    __syncthreads();
  }

  float bb[4];
#pragma unroll
  for (int j = 0; j < 4; ++j) bb[j] = bias[n0 + tx4 + j];
#pragma unroll
  for (int i = 0; i < 4; ++i) {
    const size_t row = (size_t)(m0 + ty4 + i);
    if (SPLIT) {
      ushort4 h4, l4;
      u16 hs[4], ls[4];
#pragma unroll
      for (int j = 0; j < 4; ++j) {
        float v = acc[i][j] + bb[j];
        if (RELU) v = v > 0.0f ? v : 0.0f;
        fsplit(v, hs[j], ls[j]);
      }
      h4.x = hs[0]; h4.y = hs[1]; h4.z = hs[2]; h4.w = hs[3];
      l4.x = ls[0]; l4.y = ls[1]; l4.z = ls[2]; l4.w = ls[3];
      *(ushort4*)(&Chi[row * Nn + n0 + tx4]) = h4;
      *(ushort4*)(&Clo[row * Nn + n0 + tx4]) = l4;
    } else {
      float4 o;
      float vv[4];
#pragma unroll
      for (int j = 0; j < 4; ++j) {
        float v = acc[i][j] + bb[j];
        if (RELU) v = v > 0.0f ? v : 0.0f;
        vv[j] = v;
      }
      o.x = vv[0]; o.y = vv[1]; o.z = vv[2]; o.w = vv[3];
      *(float4*)(&C[row * Nn + n0 + tx4]) = o;
    }
  }
}

// ---------------------------------------------------------------------------
// Single-product f16 MFMA GEMM (decoder only).
// ---------------------------------------------------------------------------
template <bool RELU, bool F16OUT>
__global__ __launch_bounds__(256) void gemm_mfma_f16(
    const u16* __restrict__ Ahi, const u16* __restrict__ BThi,
    const float* __restrict__ bias,
    float* __restrict__ C, u16* __restrict__ Chi,
    int M, int K, int Nn) {
  __shared__ __attribute__((aligned(16))) u16 As[64 * 32];
  __shared__ __attribute__((aligned(16))) u16 Bs[128 * 32];
  const int tid = threadIdx.x;
  const int w = tid >> 6, l = tid & 63;
  const int wr = w >> 1, wc = w & 1;
  const int lr = l & 15, g = l >> 4;
  const int m0 = blockIdx.y * 64, n0 = blockIdx.x * 128;

  f32x4 acc[2][4];
#pragma unroll
  for (int mr = 0; mr < 2; ++mr)
#pragma unroll
    for (int nr = 0; nr < 4; ++nr) acc[mr][nr] = (f32x4)0.0f;

  for (int ks = 0; ks < K / 32; ++ks) {
    const int k0 = ks * 32;
    __syncthreads();
    stage16(Ahi, m0 + w * 16, w * 16, k0, As + w * 16 * 32, l, K);
    stage16(BThi, n0 + w * 16, w * 16, k0, Bs + w * 16 * 32, l, K);
    stage16(BThi, n0 + (w + 4) * 16, (w + 4) * 16, k0, Bs + (w + 4) * 16 * 32, l, K);
    __syncthreads();

    f16x8 ah[2], bh[4];
#pragma unroll
    for (int mr = 0; mr < 2; ++mr) {
      const int ra = wr * 32 + mr * 16 + lr;
      ah[mr] = *(const f16x8*)(As + ra * 32 + (g ^ SWZ(ra)) * 8);
    }
#pragma unroll
    for (int nr = 0; nr < 4; ++nr) {
      const int rb = wc * 64 + nr * 16 + lr;
      bh[nr] = *(const f16x8*)(Bs + rb * 32 + (g ^ SWZ(rb)) * 8);
    }
#pragma unroll
    for (int mr = 0; mr < 2; ++mr)
#pragma unroll
      for (int nr = 0; nr < 4; ++nr)
        acc[mr][nr] = __builtin_amdgcn_mfma_f32_16x16x32_f16(
            ah[mr], bh[nr], acc[mr][nr], 0, 0, 0);
  }

#pragma unroll
  for (int nr = 0; nr < 4; ++nr) {
    const int col = n0 + wc * 64 + nr * 16 + lr;
    const float bb = bias[col];
#pragma unroll
    for (int mr = 0; mr < 2; ++mr) {
#pragma unroll
      for (int q = 0; q < 4; ++q) {
        const int row = m0 + wr * 32 + mr * 16 + g * 4 + q;
        float v = acc[mr][nr][q] + bb;
        if (RELU) v = v > 0.0f ? v : 0.0f;
        if (F16OUT) Chi[(size_t)row * Nn + col] = f2h_bits(v);
        else C[(size_t)row * Nn + col] = v;
      }
    }
  }
}

// ---------------------------------------------------------------------------
__global__ __launch_bounds__(256) void wtsplit(
    const float* __restrict__ W, u16* __restrict__ Thi, u16* __restrict__ Tlo,
    int K, int N) {
  __shared__ float tile[32][33];
  const int k0 = blockIdx.y * 32, n0 = blockIdx.x * 32;
  const int c = threadIdx.x & 31, r8 = threadIdx.x >> 5;
#pragma unroll
  for (int p = 0; p < 4; ++p) {
    const int r = r8 + p * 8;
    tile[r][c] = W[(size_t)(k0 + r) * N + n0 + c];
  }
  __syncthreads();
#pragma unroll
  for (int p = 0; p < 4; ++p) {
    const int r = r8 + p * 8;
    float v = tile[c][r];
    u16 hh, ll;
    fsplit(v, hh, ll);
    Thi[(size_t)(n0 + r) * K + k0 + c] = hh;
    Tlo[(size_t)(n0 + r) * K + k0 + c] = ll;
  }
}

// ---------------------------------------------------------------------------
// Codebook split: only HI plane needed (pass-1 hi*hi; pass-2 uses f32 cb).
// ---------------------------------------------------------------------------
__global__ __launch_bounds__(256) void cbsplit_kernel(
    const float* __restrict__ cb, u16* __restrict__ hi) {
  const size_t i4 = (size_t)blockIdx.x * 256 + threadIdx.x;
  float4 v = *(const float4*)(cb + i4 * 4);
  ushort4 h4;
  u16 dummy;
  fsplit(v.x, h4.x, dummy);
  fsplit(v.y, h4.y, dummy);
  fsplit(v.z, h4.z, dummy);
  fsplit(v.w, h4.w, dummy);
  *(ushort4*)(hi + i4 * 4) = h4;
}

// ---------------------------------------------------------------------------
// Codebook squared norms: f64 (exact, for pass-2) + f32 (for pass-1).
// ---------------------------------------------------------------------------
__global__ __launch_bounds__(256) void cnorm_kernel(
    const float* __restrict__ cb, double* __restrict__ cn,
    float* __restrict__ cnf) {
  const int w = blockIdx.x * 4 + (threadIdx.x >> 6);
  const int lane = threadIdx.x & 63;
  const float* row = cb + (size_t)w * HID;
  double s = 0.0;
  for (int h = lane; h < HID; h += 64) {
    double v = (double)row[h];
    s += v * v;
  }
#pragma unroll
  for (int off = 32; off > 0; off >>= 1) s += __shfl_down(s, off, 64);
  if (lane == 0) { cn[w] = s; cnf[w] = (float)s; }
}

// ---------------------------------------------------------------------------
// PASS 1 (screen only — exactness lives in pass 2). r13 body with K-step 64:
// both 32-wide k-halves staged behind ONE barrier pair (6 stage16), then
// 2x8 MFMAs (halves sequential via unroll 1 -> register reuse, VGPR ~85,
// no 128 cliff; r7's failure was 124->132). Barriers/chunk halve: 32 -> 16.
// Occupancy is pinned at 2 blocks/CU for this family (r6/r14/r15 all nulled
// grid-based levers) — this attacks stall-per-barrier instead.
// Accumulation order ks-ascending, identical to r13 -> p1 output bit-identical.
// ---------------------------------------------------------------------------
__global__ __launch_bounds__(256) void rvq_argmin_p1(
    const u16* __restrict__ Ahi, const u16* __restrict__ Bhi,
    const float* __restrict__ cnf, float* __restrict__ cand) {
  __shared__ __attribute__((aligned(16))) u16 As[2][64 * 32];    // 8 KB
  __shared__ __attribute__((aligned(16))) u16 Bs[2][128 * 32];   // 16 KB
  __shared__ float4 mt[64][16];                                  // 16 KB

  const int tid = threadIdx.x;
  const int w = tid >> 6, l = tid & 63;
  const int wr = w >> 1, wc = w & 1;
  const int lr = l & 15, g = l >> 4;
  const int bg = (blockIdx.x & 7) * 64 + (blockIdx.x >> 3);
  const int m0 = bg * 64;

  float d0[2][4], d1[2][4];
  int i0[2][4], i1[2][4];
#pragma unroll
  for (int mr = 0; mr < 2; ++mr)
#pragma unroll
    for (int q = 0; q < 4; ++q) {
      d0[mr][q] = 3.4e38f; d1[mr][q] = 3.4e38f;
      i0[mr][q] = 0; i1[mr][q] = 0;
    }

  for (int chunk = 0; chunk < KCB / 128; ++chunk) {
    const int cbase = chunk * 128;
    f32x4 acc[2][4];
#pragma unroll
    for (int mr = 0; mr < 2; ++mr)
#pragma unroll
      for (int nr = 0; nr < 4; ++nr) acc[mr][nr] = (f32x4)0.0f;

    for (int ks8 = 0; ks8 < HID / 64; ++ks8) {
      const int k0 = ks8 * 64;
      __syncthreads();
#pragma unroll
      for (int h = 0; h < 2; ++h) {
        const int kh = k0 + h * 32;
        stage16(Ahi, m0 + w * 16, w * 16, kh, As[h] + w * 16 * 32, l, HID);
        stage16(Bhi, cbase + w * 16, w * 16, kh, Bs[h] + w * 16 * 32, l, HID);
        stage16(Bhi, cbase + (w + 4) * 16, (w + 4) * 16, kh, Bs[h] + (w + 4) * 16 * 32, l, HID);
      }
      __syncthreads();

#pragma unroll 1
      for (int h = 0; h < 2; ++h) {
        f16x8 ah[2], bh[4];
#pragma unroll
        for (int mr = 0; mr < 2; ++mr) {
          const int ra = wr * 32 + mr * 16 + lr;
          ah[mr] = *(const f16x8*)(As[h] + ra * 32 + (g ^ SWZ(ra)) * 8);
        }
#pragma unroll
        for (int nr = 0; nr < 4; ++nr) {
          const int rb = wc * 64 + nr * 16 + lr;
          bh[nr] = *(const f16x8*)(Bs[h] + rb * 32 + (g ^ SWZ(rb)) * 8);
        }
#pragma unroll
        for (int mr = 0; mr < 2; ++mr)
#pragma unroll
          for (int nr = 0; nr < 4; ++nr)
            acc[mr][nr] = __builtin_amdgcn_mfma_f32_16x16x32_f16(
                ah[mr], bh[nr], acc[mr][nr], 0, 0, 0);
      }
    }

    // f32 epilogue: top-2 insert per token-slot (unchanged from r13)
#pragma unroll
    for (int nr = 0; nr < 4; ++nr) {
      const int code = cbase + wc * 64 + nr * 16 + lr;
      const float cf = cnf[code];
#pragma unroll
      for (int mr = 0; mr < 2; ++mr) {
#pragma unroll
        for (int q = 0; q < 4; ++q) {
          float d = fmaf(-2.0f, acc[mr][nr][q], cf);
          if (d < d1[mr][q]) {
            if (d < d0[mr][q]) {
              d1[mr][q] = d0[mr][q]; i1[mr][q] = i0[mr][q];
              d0[mr][q] = d; i0[mr][q] = code;
            } else {
              d1[mr][q] = d; i1[mr][q] = code;
            }
          }
        }
      }
    }
  }

  // merge wc=1 into wc=0 via LDS, write 2 entries per (token, lr)
  __syncthreads();
  if (wc == 1) {
#pragma unroll
    for (int mr = 0; mr < 2; ++mr)
#pragma unroll
      for (int q = 0; q < 4; ++q) {
        const int tl = wr * 32 + mr * 16 + g * 4 + q;
        float4 e;
        e.x = d0[mr][q]; e.y = (float)i0[mr][q];
        e.z = d1[mr][q]; e.w = (float)i1[mr][q];
        mt[tl][lr] = e;
      }
  }
  __syncthreads();
  if (wc == 0) {
#pragma unroll
    for (int mr = 0; mr < 2; ++mr)
#pragma unroll
      for (int q = 0; q < 4; ++q) {
        const int tl = wr * 32 + mr * 16 + g * 4 + q;
        float4 o = mt[tl][lr];
        float e0d = d0[mr][q], e1d = d1[mr][q];
        int e0i = i0[mr][q], e1i = i1[mr][q];
        int oi0 = (int)o.y, oi1 = (int)o.w;
        if (o.x < e1d) {
          if (o.x < e0d) { e1d = e0d; e1i = e0i; e0d = o.x; e0i = oi0; }
          else { e1d = o.x; e1i = oi0; }
        }
        if (o.z < e1d) {
          if (o.z < e0d) { e1d = e0d; e1i = e0i; e0d = o.z; e0i = oi1; }
          else { e1d = o.z; e1i = oi1; }
        }
        float4 out;
        out.x = e0d; out.y = (float)e0i; out.z = e1d; out.w = (float)e1i;
        *(float4*)(cand + ((size_t)(m0 + tl) * 32 + lr * 2) * 2) = out;
      }
  }
}

// ---------------------------------------------------------------------------
// PASS 2 (unchanged, r13-proven): min of pass-1 d; entries within MARGIN
// recomputed exactly: d = cn - 2*dot(r, cb) in f64 (r from splits, cb f32).
// f64 compare + smallest-index tie-break.
// ---------------------------------------------------------------------------
__global__ __launch_bounds__(256) void rvq_argmin_p2(
    const float* __restrict__ cand,
    const u16* __restrict__ rhi, const u16* __restrict__ rlo,
    const float* __restrict__ cb, const double* __restrict__ cn,
    int* __restrict__ idxbuf, float* __restrict__ idxout) {
  const int tid = threadIdx.x;
  const int wv = tid >> 6, l = tid & 63;
  const int t = blockIdx.x * 4 + wv;

  float ed = 3.4e38f;
  int ei = 0;
  if (l < 32) {
    float2 e = *(const float2*)(cand + ((size_t)t * 32 + l) * 2);
    ed = e.x;
    ei = (int)e.y;
  }
  float dmin = ed;
#pragma unroll
  for (int off = 32; off > 0; off >>= 1)
    dmin = fminf(dmin, __shfl_xor(dmin, off, 64));
  const bool flag = (l < 32) && (ed <= dmin + MARGIN);
  unsigned long long mask = __ballot(flag);

  const ushort4* hp = (const ushort4*)(rhi + (size_t)t * HID + l * 8);
  const ushort4* lp = (const ushort4*)(rlo + (size_t)t * HID + l * 8);
  ushort4 h0 = hp[0], h1 = hp[1], l0 = lp[0], l1 = lp[1];
  float r[8];
  r[0] = h_bits2f(h0.x) + h_bits2f(l0.x) * (1.0f / 2048.0f);
  r[1] = h_bits2f(h0.y) + h_bits2f(l0.y) * (1.0f / 2048.0f);
  r[2] = h_bits2f(h0.z) + h_bits2f(l0.z) * (1.0f / 2048.0f);
  r[3] = h_bits2f(h0.w) + h_bits2f(l0.w) * (1.0f / 2048.0f);
  r[4] = h_bits2f(h1.x) + h_bits2f(l1.x) * (1.0f / 2048.0f);
  r[5] = h_bits2f(h1.y) + h_bits2f(l1.y) * (1.0f / 2048.0f);
  r[6] = h_bits2f(h1.z) + h_bits2f(l1.z) * (1.0f / 2048.0f);
  r[7] = h_bits2f(h1.w) + h_bits2f(l1.w) * (1.0f / 2048.0f);

  double bd = 1e300;
  int bi = 0;
  while (mask) {
    const int src = __builtin_ctzll(mask);
    mask &= mask - 1;
    const int idx = __shfl(ei, src, 64);
    const float4* crow = (const float4*)(cb + (size_t)idx * HID + l * 8);
    float4 c0 = crow[0], c1 = crow[1];
    double s = (double)r[0] * (double)c0.x + (double)r[1] * (double)c0.y
             + (double)r[2] * (double)c0.z + (double)r[3] * (double)c0.w
             + (double)r[4] * (double)c1.x + (double)r[5] * (double)c1.y
             + (double)r[6] * (double)c1.z + (double)r[7] * (double)c1.w;
#pragma unroll
    for (int off = 32; off > 0; off >>= 1) s += __shfl_xor(s, off, 64);
    const double d = cn[idx] - 2.0 * s;
    if (d < bd || (d == bd && idx < bi)) { bd = d; bi = idx; }
  }
  if (l == 0) {
    idxbuf[t] = bi;
    idxout[t] = (float)bi;
  }
}

// ---------------------------------------------------------------------------
// Gather sel; quant += sel; resid(split) -= sel.
// FIRST: quant starts at 0. LAST: splits <- fsplit(quant) for the decoder.
// ---------------------------------------------------------------------------
template <bool FIRST, bool LAST>
__global__ __launch_bounds__(256) void rvq_update(
    const float* __restrict__ cb, const int* __restrict__ idxbuf,
    float* __restrict__ quant, u16* __restrict__ rhi, u16* __restrict__ rlo) {
  const size_t gid = (size_t)blockIdx.x * blockDim.x + threadIdx.x;
  const int t = (int)(gid >> 7);
  const int q4 = (int)(gid & 127);
  const int idx = idxbuf[t];
  const float4 c = *((const float4*)(cb + (size_t)idx * HID) + q4);
  float4* qp = (float4*)(quant + (size_t)t * HID) + q4;
  float cc[4] = {c.x, c.y, c.z, c.w};
  float qn[4];
  if (FIRST) {
    qn[0] = cc[0]; qn[1] = cc[1]; qn[2] = cc[2]; qn[3] = cc[3];
  } else {
    float4 qv = *qp;
    qn[0] = qv.x + cc[0]; qn[1] = qv.y + cc[1];
    qn[2] = qv.z + cc[2]; qn[3] = qv.w + cc[3];
  }
  ushort4* hp = (ushort4*)(rhi + (size_t)t * HID) + q4;
  ushort4* lp = (ushort4*)(rlo + (size_t)t * HID) + q4;
  ushort4 h4 = *hp, l4 = *lp;
  u16 hs[4] = {h4.x, h4.y, h4.z, h4.w}, ls[4] = {l4.x, l4.y, l4.z, l4.w};
#pragma unroll
  for (int j = 0; j < 4; ++j) {
    if (LAST) {
      fsplit(qn[j], hs[j], ls[j]);
    } else {
      float r = h_bits2f(hs[j]) + h_bits2f(ls[j]) * (1.0f / 2048.0f) - cc[j];
      fsplit(r, hs[j], ls[j]);
    }
  }
  float4 qo;
  qo.x = qn[0]; qo.y = qn[1]; qo.z = qn[2]; qo.w = qn[3];
  *qp = qo;
  h4.x = hs[0]; h4.y = hs[1]; h4.z = hs[2]; h4.w = hs[3];
  l4.x = ls[0]; l4.y = ls[1]; l4.z = ls[2]; l4.w = ls[3];
  *hp = h4;
  *lp = l4;
}

// ---------------------------------------------------------------------------
extern "C" void kernel_launch(void* const* d_in, const int* in_sizes, int n_in,
                              void* d_out, int out_size, void* d_ws, size_t ws_size,
                              hipStream_t stream) {
  const float* x      = (const float*)d_in[0];
  const float* enc_w1 = (const float*)d_in[1];
  const float* enc_b1 = (const float*)d_in[2];
  const float* enc_w2 = (const float*)d_in[3];
  const float* enc_b2 = (const float*)d_in[4];
  const float* dec_w1 = (const float*)d_in[5];
  const float* dec_b1 = (const float*)d_in[6];
  const float* dec_w2 = (const float*)d_in[7];
  const float* dec_b2 = (const float*)d_in[8];
  const float* cbs    = (const float*)d_in[9];

  float* quant  = (float*)d_out;
  float* idxout = quant + (size_t)N_TOK * HID;
  float* recon  = idxout + (size_t)NCB * N_TOK;

  // workspace (~94.5 MB) — r13 layout
  char* wsp = (char*)d_ws;
  u16* rhi = (u16*)wsp;       wsp += (size_t)N_TOK * HID * 2;
  u16* rlo = (u16*)wsp;       wsp += (size_t)N_TOK * HID * 2;
  u16* whi = (u16*)wsp;       wsp += (size_t)2560 * 1024 * 2;
  u16* wlo = (u16*)wsp;       wsp += (size_t)2560 * 1024 * 2;
  char* h1region = wsp;       wsp += (size_t)CHUNK_E * H2 * 4;
  int* idxbuf = (int*)wsp;    wsp += (size_t)NCB * N_TOK * 4;
  double* cn = (double*)wsp;  wsp += (size_t)NCB * KCB * 8;
  float* cnf = (float*)wsp;   wsp += (size_t)NCB * KCB * 4;

  u16* dw1Thi = whi;              u16* dw1Tlo = wlo;
  u16* dw2Thi = whi + 524288;     u16* dw2Tlo = wlo + 524288;

  float* h1f  = (float*)h1region;                     // enc hidden (f32)
  u16*   h1hi = (u16*)h1region;                       // dec hidden (f16)
  u16*   cbshi = (u16*)h1region;                      // RVQ: hi-plane cb split
  float* cand = (float*)(h1region + (size_t)KCB * HID * 2);  // 8.39 MB cand buf

  wtsplit<<<dim3(H2 / 32, HID / 32), 256, 0, stream>>>(dec_w1, dw1Thi, dw1Tlo, HID, H2);
  wtsplit<<<dim3(DIN / 32, H2 / 32), 256, 0, stream>>>(dec_w2, dw2Thi, dw2Tlo, H2, DIN);
  cnorm_kernel<<<NCB * KCB / 4, 256, 0, stream>>>(cbs, cn, cnf);

  // encoder: fp32, bit-exact k-order (index-critical)
  for (int c = 0; c < N_TOK / CHUNK_E; ++c) {
    gemm_f32ek<true, false><<<dim3(H2 / 64, CHUNK_E / 64), 256, 0, stream>>>(
        x + (size_t)c * CHUNK_E * DIN, enc_w1, enc_b1, h1f, nullptr, nullptr,
        CHUNK_E, DIN, H2);
    gemm_f32ek<false, true><<<dim3(HID / 64, CHUNK_E / 64), 256, 0, stream>>>(
        h1f, enc_w2, enc_b2, nullptr,
        rhi + (size_t)c * CHUNK_E * HID, rlo + (size_t)c * CHUNK_E * HID,
        CHUNK_E, H2, HID);
  }

  // RVQ stages: pass-1 screen (hi*hi) -> pass-2 exact refine -> update
  for (int s = 0; s < NCB; ++s) {
    const float* cb = cbs + (size_t)s * KCB * HID;
    cbsplit_kernel<<<(KCB * HID / 4) / 256, 256, 0, stream>>>(cb, cbshi);
    rvq_argmin_p1<<<N_TOK / 64, 256, 0, stream>>>(
        rhi, cbshi, cnf + (size_t)s * KCB, cand);
    rvq_argmin_p2<<<N_TOK / 4, 256, 0, stream>>>(
        cand, rhi, rlo, cb, cn + (size_t)s * KCB,
        idxbuf + (size_t)s * N_TOK, idxout + (size_t)s * N_TOK);
    if (s == 0)
      rvq_update<true, false><<<(N_TOK * 128) / 256, 256, 0, stream>>>(
          cb, idxbuf + (size_t)s * N_TOK, quant, rhi, rlo);
    else if (s < NCB - 1)
      rvq_update<false, false><<<(N_TOK * 128) / 256, 256, 0, stream>>>(
          cb, idxbuf + (size_t)s * N_TOK, quant, rhi, rlo);
    else
      rvq_update<false, true><<<(N_TOK * 128) / 256, 256, 0, stream>>>(
          cb, idxbuf + (size_t)s * N_TOK, quant, rhi, rlo);
  }

  // decoder: single-product f16 MFMA
  for (int c = 0; c < N_TOK / CHUNK_D; ++c) {
    gemm_mfma_f16<true, true><<<dim3(H2 / 128, CHUNK_D / 64), 256, 0, stream>>>(
        rhi + (size_t)c * CHUNK_D * HID, dw1Thi, dec_b1,
        nullptr, h1hi, CHUNK_D, HID, H2);
    gemm_mfma_f16<false, false><<<dim3(DIN / 128, CHUNK_D / 64), 256, 0, stream>>>(
        h1hi, dw2Thi, dec_b2,
        recon + (size_t)c * CHUNK_D * DIN, nullptr, CHUNK_D, H2, DIN);
  }
}